// Round 8
// baseline (3158.970 us; speedup 1.0000x reference)
//
#include <hip/hip_runtime.h>
#include <hip/hip_bf16.h>
#include <stdint.h>

#define IN_F 4096
#define OUT_F 4096

typedef __attribute__((ext_vector_type(8))) __bf16 bf16x8;
typedef __attribute__((ext_vector_type(4))) float f32x4;

__device__ __forceinline__ void gl_lds_16(const void* g, void* l) {
    __builtin_amdgcn_global_load_lds((const __attribute__((address_space(1))) void*)g,
                                     (__attribute__((address_space(3))) void*)l,
                                     16, 0, 0);
}

// ---- fused: x fp32->bf16 (8 elems/thread) + sorted-COO scatter (R6 form:
// scatter rides concurrently under the BW-bound cvt; memsetAsync precedes) ----
__global__ void cvt_and_scatter(const float* __restrict__ x, __bf16* __restrict__ Xb, int n8,
                                const float* __restrict__ vals, const int* __restrict__ idx,
                                __bf16* __restrict__ W, int nnz, int cvtBlocks) {
    if ((int)blockIdx.x < cvtBlocks) {
        int i = blockIdx.x * blockDim.x + threadIdx.x;
        if (i < n8) {
            const float4* src = (const float4*)(x + (size_t)i * 8);
            float4 v0 = src[0], v1 = src[1];
            bf16x8 o;
            o[0] = (__bf16)v0.x; o[1] = (__bf16)v0.y; o[2] = (__bf16)v0.z; o[3] = (__bf16)v0.w;
            o[4] = (__bf16)v1.x; o[5] = (__bf16)v1.y; o[6] = (__bf16)v1.z; o[7] = (__bf16)v1.w;
            *(bf16x8*)(Xb + (size_t)i * 8) = o;
        }
    } else {
        // flat_idx sorted -> duplicate runs adjacent; run owner sums fp32, stores bf16.
        int i = (blockIdx.x - cvtBlocks) * blockDim.x + threadIdx.x;
        if (i >= nnz) return;
        const int id = idx[i];
        if (i > 0 && idx[i - 1] == id) return;
        float s = vals[i];
        for (int j = i + 1; j < nnz && idx[j] == id; ++j) s += vals[j];
        W[id] = (__bf16)s;
    }
}

// ---- GEMM: C[M,N] = A[M,K] * B[N,K]^T + bias,  bf16 in / fp32 out ----
// 256x256 tile, BK=32, 8 waves (2Mx4N), quad-buffered LDS, prefetch distance 3,
// chunk-XOR swizzle (conflicts=0), register-double-buffered fragments,
// per-wave interleaved {3 DS_READ, 8 MFMA} groups (R7: validated).
// R8: ANTIPHASE WAVE ROLES. R7 measured 2048 cyc/tile: with all 8 waves running
// the identical program from a common barrier, the CU alternates CU-wide between
// "everyone reads" (LDS busy, MFMA idle) and "everyone MFMAs" (MFMA busy, LDS
// idle): 4 x (288 DS + 256 MFMA) = 2176 ~= measured. Fix: waves 0-3 reads-lead
// (R M R M...), waves 4-7 MFMA-lead (M R M R...) — valid since MFMAs use current
// regs and reads fill next regs. Waves w,w+4 share a SIMD, so each SIMD always
// has one wave feeding MFMA and one feeding LDS -> pipes run in antiphase.
// Sync schedule unchanged (4 rounds verified): vmcnt(4) certifies STAGE(t+2)
// before barrier@t; reads@t (buf (t+1)&3) covered by barrier@t-1; WAR on
// STAGE@t's buffer is 2 barriers upstream.
#define BM 256
#define BN 256
#define BK 32
#define NT (IN_F / BK)   // 128 K-tiles

__global__ __launch_bounds__(512, 2) void gemm_bf16_bt(
    const __bf16* __restrict__ A, const __bf16* __restrict__ B,
    const float* __restrict__ bias, float* __restrict__ C,
    int M, int N, int K)
{
    __shared__ __align__(128) __bf16 lds[4][16384];

    const int t512 = threadIdx.x;          // 0..511
    const int wave = t512 >> 6;            // 0..7
    const int lane = t512 & 63;
    const int wm = wave >> 2;              // 0..1  (M half)
    const int wn = wave & 3;               // 0..3  (N quarter)
    const int lq = lane >> 4;              // 0..3
    const int lr = lane & 15;              // 0..15

    // XCD swizzle: grid is exactly 512 = 8 XCDs x 64 contiguous slots
    const int bid  = blockIdx.x;
    const int wgid = (bid & 7) * 64 + (bid >> 3);
    const int mt = wgid >> 4;              // 0..31
    const int nt = wgid & 15;              // 0..15
    const int tileM = mt * BM;
    const int tileN = nt * BN;

    // staging: thread u covers row u>>2; DEST chunk u&3 linear (global_load_lds),
    // SOURCE chunk swizzle-inverse: c = (u&3) ^ ((row>>1)&3) = (u&3) ^ ((u>>3)&3).
    const int srow = t512 >> 2;            // 0..127
    const int scol = ((t512 & 3) ^ ((t512 >> 3) & 3)) * 8;

    const __bf16* gA0 = A + (size_t)(tileM + srow) * K + scol;
    const __bf16* gA1 = A + (size_t)(tileM + 128 + srow) * K + scol;
    const __bf16* gB0 = B + (size_t)(tileN + srow) * K + scol;
    const __bf16* gB1 = B + (size_t)(tileN + 128 + srow) * K + scol;

#define STAGE_A(buf, k0) do { \
        gl_lds_16(gA0 + (k0), &lds[buf][0]    + t512 * 8); \
        gl_lds_16(gA1 + (k0), &lds[buf][4096] + t512 * 8); } while (0)
#define STAGE_B(buf, k0) do { \
        gl_lds_16(gB0 + (k0), &lds[buf][8192]         + t512 * 8); \
        gl_lds_16(gB1 + (k0), &lds[buf][8192 + 4096]  + t512 * 8); } while (0)

    // fragment read offsets with matching XOR (row bases are multiples of 16):
    const int cswz = (lq ^ ((lr >> 1) & 3)) * 8;
    const int aoff = (wm * 128 + lr) * BK + cswz;            // fa[mi] at +mi*512
    const int boff = 8192 + (wn * 64 + lr) * BK + cswz;      // fb[ni] at +ni*512

    f32x4 acc[8][4] = {};
    bf16x8 fa0[8], fb0[4], fa1[8], fb1[4];

#define MM2(FAc, FBc, MI0, MI1) do {                                            \
        _Pragma("unroll") for (int ni_ = 0; ni_ < 4; ++ni_)                     \
            acc[MI0][ni_] = __builtin_amdgcn_mfma_f32_16x16x32_bf16(            \
                FAc[MI0], FBc[ni_], acc[MI0][ni_], 0, 0, 0);                    \
        _Pragma("unroll") for (int ni_ = 0; ni_ < 4; ++ni_)                     \
            acc[MI1][ni_] = __builtin_amdgcn_mfma_f32_16x16x32_bf16(            \
                FAc[MI1], FBc[ni_], acc[MI1][ni_], 0, 0, 0);                    \
    } while (0)

// read groups (fill next-tile frags; order chosen so next tile's M0 needs only R0+R1)
#define RG0(FAn, FBn, nb_) do { FAn[0] = *(const bf16x8*)&nb_[aoff];            \
        FAn[1] = *(const bf16x8*)&nb_[aoff + 512];                              \
        FBn[0] = *(const bf16x8*)&nb_[boff]; } while (0)
#define RG1(FAn, FBn, nb_) do { FBn[1] = *(const bf16x8*)&nb_[boff + 512];      \
        FBn[2] = *(const bf16x8*)&nb_[boff + 1024];                             \
        FBn[3] = *(const bf16x8*)&nb_[boff + 1536]; } while (0)
#define RG2(FAn, FBn, nb_) do { FAn[2] = *(const bf16x8*)&nb_[aoff + 1024];     \
        FAn[3] = *(const bf16x8*)&nb_[aoff + 1536];                             \
        FAn[4] = *(const bf16x8*)&nb_[aoff + 2048]; } while (0)
#define RG3(FAn, FBn, nb_) do { FAn[5] = *(const bf16x8*)&nb_[aoff + 2560];     \
        FAn[6] = *(const bf16x8*)&nb_[aoff + 3072];                             \
        FAn[7] = *(const bf16x8*)&nb_[aoff + 3584]; } while (0)

#define SGB_VMEM4 do { __builtin_amdgcn_sched_group_barrier(0x030, 4, 0); } while (0)
#define SGB_DS_MF do { __builtin_amdgcn_sched_group_barrier(0x100, 3, 0);       \
        __builtin_amdgcn_sched_group_barrier(0x008, 8, 0); } while (0)
#define SGB_MF_DS do { __builtin_amdgcn_sched_group_barrier(0x008, 8, 0);       \
        __builtin_amdgcn_sched_group_barrier(0x100, 3, 0); } while (0)

// main-loop tile: antiphase variants. Both end at the same per-tile barrier.
#define TILE_MAIN(T, FAc, FBc, FAn, FBn) do {                                   \
        const int t_ = (T);                                                     \
        const int pb_ = (t_ + 3) & 3; const int pk_ = (t_ + 3) * BK;            \
        const __bf16* nb_ = &lds[(t_ + 1) & 3][0];                              \
        if (wave < 4) { /* reads-lead */                                        \
            STAGE_A(pb_, pk_); STAGE_B(pb_, pk_);                               \
            RG0(FAn, FBn, nb_); MM2(FAc, FBc, 0, 1);                            \
            RG1(FAn, FBn, nb_); MM2(FAc, FBc, 2, 3);                            \
            RG2(FAn, FBn, nb_); MM2(FAc, FBc, 4, 5);                            \
            RG3(FAn, FBn, nb_); MM2(FAc, FBc, 6, 7);                            \
            SGB_VMEM4;                                                          \
            SGB_DS_MF; SGB_DS_MF; SGB_DS_MF; SGB_DS_MF;                         \
        } else { /* MFMA-lead */                                                \
            STAGE_A(pb_, pk_); STAGE_B(pb_, pk_);                               \
            MM2(FAc, FBc, 0, 1); RG0(FAn, FBn, nb_);                            \
            MM2(FAc, FBc, 2, 3); RG1(FAn, FBn, nb_);                            \
            MM2(FAc, FBc, 4, 5); RG2(FAn, FBn, nb_);                            \
            MM2(FAc, FBc, 6, 7); RG3(FAn, FBn, nb_);                            \
            SGB_VMEM4;                                                          \
            SGB_MF_DS; SGB_MF_DS; SGB_MF_DS; SGB_MF_DS;                         \
        }                                                                       \
        asm volatile("s_waitcnt vmcnt(4)" ::: "memory");                        \
        __builtin_amdgcn_s_barrier();                                           \
        asm volatile("" ::: "memory");                                          \
    } while (0)

// tail tile: literal T -> all conditionals fold at compile time.
#define TILE(T, FAc, FBc, FAn, FBn) do {                                        \
        const int t_ = (T);                                                     \
        if (t_ + 3 < NT) {                                                      \
            const int pb_ = (t_ + 3) & 3; const int pk_ = (t_ + 3) * BK;        \
            STAGE_A(pb_, pk_); STAGE_B(pb_, pk_);                               \
        }                                                                       \
        if (t_ + 1 < NT) {                                                      \
            const __bf16* nb_ = &lds[(t_ + 1) & 3][0];                          \
            _Pragma("unroll") for (int mi = 0; mi < 8; ++mi)                    \
                FAn[mi] = *(const bf16x8*)&nb_[aoff + mi * 512];                \
            _Pragma("unroll") for (int ni = 0; ni < 4; ++ni)                    \
                FBn[ni] = *(const bf16x8*)&nb_[boff + ni * 512];                \
        }                                                                       \
        _Pragma("unroll") for (int mi = 0; mi < 8; ++mi)                        \
            _Pragma("unroll") for (int ni = 0; ni < 4; ++ni)                    \
                acc[mi][ni] = __builtin_amdgcn_mfma_f32_16x16x32_bf16(          \
                    FAc[mi], FBc[ni], acc[mi][ni], 0, 0, 0);                    \
        if (t_ < NT - 3)       asm volatile("s_waitcnt vmcnt(4)" ::: "memory"); \
        else if (t_ == NT - 3) asm volatile("s_waitcnt vmcnt(0)" ::: "memory"); \
        if (t_ < NT - 1) {                                                      \
            __builtin_amdgcn_s_barrier();                                       \
            asm volatile("" ::: "memory");                                      \
        }                                                                       \
    } while (0)

    // ---- prologue: stage 0,1,2; certify stages 0+1 for ALL waves; frags(0) ----
    STAGE_A(0, 0);   STAGE_B(0, 0);
    STAGE_A(1, 32);  STAGE_B(1, 32);
    STAGE_A(2, 64);  STAGE_B(2, 64);
    asm volatile("s_waitcnt vmcnt(4)" ::: "memory");
    __builtin_amdgcn_s_barrier();
    asm volatile("" ::: "memory");
    {
        const __bf16* nb_ = &lds[0][0];
#pragma unroll
        for (int mi = 0; mi < 8; ++mi) fa0[mi] = *(const bf16x8*)&nb_[aoff + mi * 512];
#pragma unroll
        for (int ni = 0; ni < 4; ++ni) fb0[ni] = *(const bf16x8*)&nb_[boff + ni * 512];
    }

    // main loop: tiles 0..123 (t+3 <= 126 < NT and t+1 <= 124 < NT always)
    for (int t = 0; t < 124; t += 2) {
        TILE_MAIN(t,     fa0, fb0, fa1, fb1);
        TILE_MAIN(t + 1, fa1, fb1, fa0, fb0);
    }
    // tail: tiles 124..127, literal-folded conditionals
    TILE(124, fa0, fb0, fa1, fb1);
    TILE(125, fa1, fb1, fa0, fb0);
    TILE(126, fa0, fb0, fa1, fb1);
    TILE(127, fa1, fb1, fa0, fb0);

    // ---- epilogue: C/D layout col=lane&15, row=(lane>>4)*4+reg  [m89-verified] ----
    float bv[4];
#pragma unroll
    for (int ni = 0; ni < 4; ++ni) bv[ni] = bias[tileN + wn * 64 + ni * 16 + lr];
#pragma unroll
    for (int mi = 0; mi < 8; ++mi) {
#pragma unroll
        for (int ni = 0; ni < 4; ++ni) {
            const int gn = tileN + wn * 64 + ni * 16 + lr;
#pragma unroll
            for (int r = 0; r < 4; ++r) {
                const int gm = tileM + wm * 128 + mi * 16 + lq * 4 + r;
                C[(size_t)gm * N + gn] = acc[mi][ni][r] + bv[ni];
            }
        }
    }
#undef TILE
#undef TILE_MAIN
#undef MM2
#undef RG0
#undef RG1
#undef RG2
#undef RG3
#undef SGB_VMEM4
#undef SGB_DS_MF
#undef SGB_MF_DS
#undef STAGE_A
#undef STAGE_B
}

extern "C" void kernel_launch(void* const* d_in, const int* in_sizes, int n_in,
                              void* d_out, int out_size, void* d_ws, size_t ws_size,
                              hipStream_t stream) {
    const float* x    = (const float*)d_in[0];   // (4,2048,4096) fp32
    const float* vals = (const float*)d_in[1];   // (NNZ,) fp32
    const float* bias = (const float*)d_in[2];   // (4096,) fp32
    const int*   idx  = (const int*)d_in[3];     // (NNZ,) sorted flat indices
    float* out = (float*)d_out;                  // (4,2048,4096) fp32

    const int nnz = in_sizes[1];
    const int K = IN_F, N = OUT_F;
    const int M = in_sizes[0] / K;               // 8192

    // workspace: [0,32M) W bf16 | [32M,96M) x bf16
    char* ws = (char*)d_ws;
    __bf16* Wb = (__bf16*)ws;
    __bf16* Xb = (__bf16*)(ws + (size_t)32 * 1024 * 1024);

    const int wElems = N * K;                    // 16777216
    const int xElems = M * K;                    // 33554432
    const int n8 = xElems / 8;                   // 4194304 cvt threads
    const int cvtBlocks = n8 / 256;              // 16384
    const int scatBlocks = (nnz + 255) / 256;    // 6554

    hipMemsetAsync(Wb, 0, (size_t)wElems * sizeof(__bf16), stream);
    cvt_and_scatter<<<cvtBlocks + scatBlocks, 256, 0, stream>>>(
        x, Xb, n8, vals, idx, Wb, nnz, cvtBlocks);

    gemm_bf16_bt<<<(M / BM) * (N / BN), 512, 0, stream>>>(Xb, Wb, bias, out, M, N, K);
}

// Round 9
// 493.766 us; speedup vs baseline: 6.3977x; 6.3977x over previous
//
#include <hip/hip_runtime.h>
#include <hip/hip_bf16.h>
#include <stdint.h>

#define IN_F 4096
#define OUT_F 4096

typedef __attribute__((ext_vector_type(8))) __bf16 bf16x8;
typedef __attribute__((ext_vector_type(4))) float f32x4;

__device__ __forceinline__ void gl_lds_16(const void* g, void* l) {
    __builtin_amdgcn_global_load_lds((const __attribute__((address_space(1))) void*)g,
                                     (__attribute__((address_space(3))) void*)l,
                                     16, 0, 0);
}

// ---- fused pre-pass: x fp32->bf16 cvt + dense-W build from sorted COO ----
// cvt blocks: 8 elems/thread, 16B loads+stores (BW-bound, ~192MB traffic).
// build blocks: each THREAD independently binary-searches the sorted idx for
// its own 8 consecutive W elems (21 dependent L2-resident loads, hidden by
// 2.1M threads of TLP — NO __syncthreads, unlike R4's serial block searches),
// then emits zeros/run-sums as one coalesced 16B store. Eliminates the 32MB
// memset pass AND the 1.6M random 2B write-allocate stores of scatter_w.
// Per-element sum order = idx-sorted order == scatter's order (bit-identical).
__global__ void cvt_and_build(const float* __restrict__ x, __bf16* __restrict__ Xb, int n8,
                              const float* __restrict__ vals, const int* __restrict__ idx,
                              __bf16* __restrict__ W, int nnz, int cvtBlocks) {
    if ((int)blockIdx.x < cvtBlocks) {
        int i = blockIdx.x * blockDim.x + threadIdx.x;
        if (i < n8) {
            const float4* src = (const float4*)(x + (size_t)i * 8);
            float4 v0 = src[0], v1 = src[1];
            bf16x8 o;
            o[0] = (__bf16)v0.x; o[1] = (__bf16)v0.y; o[2] = (__bf16)v0.z; o[3] = (__bf16)v0.w;
            o[4] = (__bf16)v1.x; o[5] = (__bf16)v1.y; o[6] = (__bf16)v1.z; o[7] = (__bf16)v1.w;
            *(bf16x8*)(Xb + (size_t)i * 8) = o;
        }
    } else {
        const int b = (int)blockIdx.x - cvtBlocks;           // 0..8191
        const int ts = (b << 11) + (int)threadIdx.x * 8;     // this thread's 8 W elems
        int lo = 0, hi = nnz;                                 // lower_bound(idx, ts)
        while (lo < hi) { int m = (lo + hi) >> 1; if (idx[m] < ts) lo = m + 1; else hi = m; }
        int j = lo;
        bf16x8 o;
#pragma unroll
        for (int k = 0; k < 8; ++k) {                         // static k -> named regs
            float a = 0.0f;
            while (j < nnz && idx[j] == ts + k) { a += vals[j]; ++j; }
            o[k] = (__bf16)a;
        }
        *(bf16x8*)(W + ts) = o;
    }
}

// ---- GEMM: C[M,N] = A[M,K] * B[N,K]^T + bias,  bf16 in / fp32 out ----
// EXACT R7 revert (verified 218.5us, MfmaUtil 56, conflicts 0). R8's antiphase
// wave-role if/else spilled the register-carried loop state to scratch
// (WRITE_SIZE 131MB -> 7.6GB, 14x slowdown): per-wave code-path splits that
// duplicate the fragment/acc-carrying body are OFF LIMITS in plain HIP.
// Structure: 256x256 tile, BK=32, 8 waves (2Mx4N), quad-buffered LDS, prefetch
// distance 3, chunk-XOR swizzle, register-double-buffered fragments,
// source-order interleave 4 x {<=2 VMEM, 3 DS_READ, 8 MFMA} + SGB chain in one
// unbroken scheduling region (NO setprio inside — it splits the region, R6).
// Sync: vmcnt(4) certifies STAGE(t+2) before barrier@t; reads@t (buf (t+1)&3)
// covered by barrier@t-1; WAR on STAGE@t's buffer is 2 barriers upstream.
#define BM 256
#define BN 256
#define BK 32
#define NT (IN_F / BK)   // 128 K-tiles

__global__ __launch_bounds__(512, 2) void gemm_bf16_bt(
    const __bf16* __restrict__ A, const __bf16* __restrict__ B,
    const float* __restrict__ bias, float* __restrict__ C,
    int M, int N, int K)
{
    __shared__ __align__(128) __bf16 lds[4][16384];

    const int t512 = threadIdx.x;          // 0..511
    const int wave = t512 >> 6;            // 0..7
    const int lane = t512 & 63;
    const int wm = wave >> 2;              // 0..1  (M half)
    const int wn = wave & 3;               // 0..3  (N quarter)
    const int lq = lane >> 4;              // 0..3
    const int lr = lane & 15;              // 0..15

    // XCD swizzle: grid is exactly 512 = 8 XCDs x 64 contiguous slots
    const int bid  = blockIdx.x;
    const int wgid = (bid & 7) * 64 + (bid >> 3);
    const int mt = wgid >> 4;              // 0..31
    const int nt = wgid & 15;              // 0..15
    const int tileM = mt * BM;
    const int tileN = nt * BN;

    // staging: thread u covers row u>>2; DEST chunk u&3 linear (global_load_lds),
    // SOURCE chunk swizzle-inverse: c = (u&3) ^ ((row>>1)&3) = (u&3) ^ ((u>>3)&3).
    const int srow = t512 >> 2;            // 0..127
    const int scol = ((t512 & 3) ^ ((t512 >> 3) & 3)) * 8;

    const __bf16* gA0 = A + (size_t)(tileM + srow) * K + scol;
    const __bf16* gA1 = A + (size_t)(tileM + 128 + srow) * K + scol;
    const __bf16* gB0 = B + (size_t)(tileN + srow) * K + scol;
    const __bf16* gB1 = B + (size_t)(tileN + 128 + srow) * K + scol;

#define STAGE_A(buf, k0) do { \
        gl_lds_16(gA0 + (k0), &lds[buf][0]    + t512 * 8); \
        gl_lds_16(gA1 + (k0), &lds[buf][4096] + t512 * 8); } while (0)
#define STAGE_B(buf, k0) do { \
        gl_lds_16(gB0 + (k0), &lds[buf][8192]         + t512 * 8); \
        gl_lds_16(gB1 + (k0), &lds[buf][8192 + 4096]  + t512 * 8); } while (0)

    // fragment read offsets with matching XOR (row bases are multiples of 16):
    const int cswz = (lq ^ ((lr >> 1) & 3)) * 8;
    const int aoff = (wm * 128 + lr) * BK + cswz;            // fa[mi] at +mi*512
    const int boff = 8192 + (wn * 64 + lr) * BK + cswz;      // fb[ni] at +ni*512

    f32x4 acc[8][4] = {};
    bf16x8 fa0[8], fb0[4], fa1[8], fb1[4];

#define MM2(FAc, FBc, MI0, MI1) do {                                            \
        _Pragma("unroll") for (int ni_ = 0; ni_ < 4; ++ni_)                     \
            acc[MI0][ni_] = __builtin_amdgcn_mfma_f32_16x16x32_bf16(            \
                FAc[MI0], FBc[ni_], acc[MI0][ni_], 0, 0, 0);                    \
        _Pragma("unroll") for (int ni_ = 0; ni_ < 4; ++ni_)                     \
            acc[MI1][ni_] = __builtin_amdgcn_mfma_f32_16x16x32_bf16(            \
                FAc[MI1], FBc[ni_], acc[MI1][ni_], 0, 0, 0);                    \
    } while (0)

// main-loop tile (tiles 0..123: always stage + always read-ahead), interleaved.
#define TILE_MAIN(T, FAc, FBc, FAn, FBn) do {                                   \
        const int t_ = (T);                                                     \
        const int pb_ = (t_ + 3) & 3; const int pk_ = (t_ + 3) * BK;            \
        const __bf16* nb_ = &lds[(t_ + 1) & 3][0];                              \
        /* G0: 2 VMEM, 3 DS, 8 MFMA */                                          \
        STAGE_A(pb_, pk_);                                                      \
        FAn[0] = *(const bf16x8*)&nb_[aoff];                                    \
        FAn[1] = *(const bf16x8*)&nb_[aoff + 512];                              \
        FBn[0] = *(const bf16x8*)&nb_[boff];                                    \
        MM2(FAc, FBc, 0, 1);                                                    \
        /* G1: 2 VMEM, 3 DS, 8 MFMA */                                          \
        STAGE_B(pb_, pk_);                                                      \
        FBn[1] = *(const bf16x8*)&nb_[boff + 512];                              \
        FBn[2] = *(const bf16x8*)&nb_[boff + 1024];                             \
        FBn[3] = *(const bf16x8*)&nb_[boff + 1536];                             \
        MM2(FAc, FBc, 2, 3);                                                    \
        /* G2: 3 DS, 8 MFMA */                                                  \
        FAn[2] = *(const bf16x8*)&nb_[aoff + 1024];                             \
        FAn[3] = *(const bf16x8*)&nb_[aoff + 1536];                             \
        FAn[4] = *(const bf16x8*)&nb_[aoff + 2048];                             \
        MM2(FAc, FBc, 4, 5);                                                    \
        /* G3: 3 DS, 8 MFMA */                                                  \
        FAn[5] = *(const bf16x8*)&nb_[aoff + 2560];                             \
        FAn[6] = *(const bf16x8*)&nb_[aoff + 3072];                             \
        FAn[7] = *(const bf16x8*)&nb_[aoff + 3584];                             \
        MM2(FAc, FBc, 6, 7);                                                    \
        /* SGB prescription for THIS region (no setprio/asm inside region) */   \
        __builtin_amdgcn_sched_group_barrier(0x030, 2, 0); /* 2 VMEM  */        \
        __builtin_amdgcn_sched_group_barrier(0x100, 3, 0); /* 3 DS_rd */        \
        __builtin_amdgcn_sched_group_barrier(0x008, 8, 0); /* 8 MFMA  */        \
        __builtin_amdgcn_sched_group_barrier(0x030, 2, 0);                      \
        __builtin_amdgcn_sched_group_barrier(0x100, 3, 0);                      \
        __builtin_amdgcn_sched_group_barrier(0x008, 8, 0);                      \
        __builtin_amdgcn_sched_group_barrier(0x100, 3, 0);                      \
        __builtin_amdgcn_sched_group_barrier(0x008, 8, 0);                      \
        __builtin_amdgcn_sched_group_barrier(0x100, 3, 0);                      \
        __builtin_amdgcn_sched_group_barrier(0x008, 8, 0);                      \
        asm volatile("s_waitcnt vmcnt(4)" ::: "memory");                        \
        __builtin_amdgcn_s_barrier();                                           \
        asm volatile("" ::: "memory");                                          \
    } while (0)

// tail tile: literal T -> all conditionals fold at compile time.
#define TILE(T, FAc, FBc, FAn, FBn) do {                                        \
        const int t_ = (T);                                                     \
        if (t_ + 3 < NT) {                                                      \
            const int pb_ = (t_ + 3) & 3; const int pk_ = (t_ + 3) * BK;        \
            STAGE_A(pb_, pk_); STAGE_B(pb_, pk_);                               \
        }                                                                       \
        if (t_ + 1 < NT) {                                                      \
            const __bf16* nb_ = &lds[(t_ + 1) & 3][0];                          \
            _Pragma("unroll") for (int mi = 0; mi < 8; ++mi)                    \
                FAn[mi] = *(const bf16x8*)&nb_[aoff + mi * 512];                \
            _Pragma("unroll") for (int ni = 0; ni < 4; ++ni)                    \
                FBn[ni] = *(const bf16x8*)&nb_[boff + ni * 512];                \
        }                                                                       \
        _Pragma("unroll") for (int mi = 0; mi < 8; ++mi)                        \
            _Pragma("unroll") for (int ni = 0; ni < 4; ++ni)                    \
                acc[mi][ni] = __builtin_amdgcn_mfma_f32_16x16x32_bf16(          \
                    FAc[mi], FBc[ni], acc[mi][ni], 0, 0, 0);                    \
        if (t_ < NT - 3)       asm volatile("s_waitcnt vmcnt(4)" ::: "memory"); \
        else if (t_ == NT - 3) asm volatile("s_waitcnt vmcnt(0)" ::: "memory"); \
        if (t_ < NT - 1) {                                                      \
            __builtin_amdgcn_s_barrier();                                       \
            asm volatile("" ::: "memory");                                      \
        }                                                                       \
    } while (0)

    // ---- prologue: stage 0,1,2; certify stages 0+1 for ALL waves; frags(0) ----
    STAGE_A(0, 0);   STAGE_B(0, 0);
    STAGE_A(1, 32);  STAGE_B(1, 32);
    STAGE_A(2, 64);  STAGE_B(2, 64);
    asm volatile("s_waitcnt vmcnt(4)" ::: "memory");
    __builtin_amdgcn_s_barrier();
    asm volatile("" ::: "memory");
    {
        const __bf16* nb_ = &lds[0][0];
#pragma unroll
        for (int mi = 0; mi < 8; ++mi) fa0[mi] = *(const bf16x8*)&nb_[aoff + mi * 512];
#pragma unroll
        for (int ni = 0; ni < 4; ++ni) fb0[ni] = *(const bf16x8*)&nb_[boff + ni * 512];
    }

    // main loop: tiles 0..123 (t+3 <= 126 < NT and t+1 <= 124 < NT always)
    for (int t = 0; t < 124; t += 2) {
        TILE_MAIN(t,     fa0, fb0, fa1, fb1);
        TILE_MAIN(t + 1, fa1, fb1, fa0, fb0);
    }
    // tail: tiles 124..127, literal-folded conditionals
    TILE(124, fa0, fb0, fa1, fb1);
    TILE(125, fa1, fb1, fa0, fb0);
    TILE(126, fa0, fb0, fa1, fb1);
    TILE(127, fa1, fb1, fa0, fb0);

    // ---- epilogue: C/D layout col=lane&15, row=(lane>>4)*4+reg  [m89-verified] ----
    float bv[4];
#pragma unroll
    for (int ni = 0; ni < 4; ++ni) bv[ni] = bias[tileN + wn * 64 + ni * 16 + lr];
#pragma unroll
    for (int mi = 0; mi < 8; ++mi) {
#pragma unroll
        for (int ni = 0; ni < 4; ++ni) {
            const int gn = tileN + wn * 64 + ni * 16 + lr;
#pragma unroll
            for (int r = 0; r < 4; ++r) {
                const int gm = tileM + wm * 128 + mi * 16 + lq * 4 + r;
                C[(size_t)gm * N + gn] = acc[mi][ni][r] + bv[ni];
            }
        }
    }
#undef TILE
#undef TILE_MAIN
#undef MM2
#undef STAGE_A
#undef STAGE_B
}

extern "C" void kernel_launch(void* const* d_in, const int* in_sizes, int n_in,
                              void* d_out, int out_size, void* d_ws, size_t ws_size,
                              hipStream_t stream) {
    const float* x    = (const float*)d_in[0];   // (4,2048,4096) fp32
    const float* vals = (const float*)d_in[1];   // (NNZ,) fp32
    const float* bias = (const float*)d_in[2];   // (4096,) fp32
    const int*   idx  = (const int*)d_in[3];     // (NNZ,) sorted flat indices
    float* out = (float*)d_out;                  // (4,2048,4096) fp32

    const int nnz = in_sizes[1];
    const int K = IN_F, N = OUT_F;
    const int M = in_sizes[0] / K;               // 8192

    // workspace: [0,32M) W bf16 | [32M,96M) x bf16
    char* ws = (char*)d_ws;
    __bf16* Wb = (__bf16*)ws;
    __bf16* Xb = (__bf16*)(ws + (size_t)32 * 1024 * 1024);

    const int wElems = N * K;                    // 16777216
    const int xElems = M * K;                    // 33554432
    const int n8 = xElems / 8;                   // 4194304 cvt threads
    const int cvtBlocks = n8 / 256;              // 16384
    const int buildBlocks = wElems / 2048;       // 8192 (covers W exactly, no memset)

    // single pre-pass dispatch: no memset, no random scatter stores.
    cvt_and_build<<<cvtBlocks + buildBlocks, 256, 0, stream>>>(
        x, Xb, n8, vals, idx, Wb, nnz, cvtBlocks);

    gemm_bf16_bt<<<(M / BM) * (N / BN), 512, 0, stream>>>(Xb, Wb, bias, out, M, N, K);
}

// Round 10
// 453.180 us; speedup vs baseline: 6.9707x; 1.0896x over previous
//
#include <hip/hip_runtime.h>
#include <hip/hip_bf16.h>
#include <stdint.h>

#define IN_F 4096
#define OUT_F 4096

typedef __attribute__((ext_vector_type(8))) __bf16 bf16x8;
typedef __attribute__((ext_vector_type(4))) float f32x4;

__device__ __forceinline__ void gl_lds_16(const void* g, void* l) {
    __builtin_amdgcn_global_load_lds((const __attribute__((address_space(1))) void*)g,
                                     (__attribute__((address_space(3))) void*)l,
                                     16, 0, 0);
}

// ---- fused: x fp32->bf16 (8 elems/thread) + sorted-COO scatter ----
// FINAL pre-pass form. Search-based W builds failed twice (R4 block-search
// +51us, R9 thread-search +42us): 2.1M x ~21 dependent random idx probes +
// full-32MB scattered store coverage loses to memset's linear fill + ~3MB
// semi-sorted scatter stores. Do not re-attempt.
__global__ void cvt_and_scatter(const float* __restrict__ x, __bf16* __restrict__ Xb, int n8,
                                const float* __restrict__ vals, const int* __restrict__ idx,
                                __bf16* __restrict__ W, int nnz, int cvtBlocks) {
    if ((int)blockIdx.x < cvtBlocks) {
        int i = blockIdx.x * blockDim.x + threadIdx.x;
        if (i < n8) {
            const float4* src = (const float4*)(x + (size_t)i * 8);
            float4 v0 = src[0], v1 = src[1];
            bf16x8 o;
            o[0] = (__bf16)v0.x; o[1] = (__bf16)v0.y; o[2] = (__bf16)v0.z; o[3] = (__bf16)v0.w;
            o[4] = (__bf16)v1.x; o[5] = (__bf16)v1.y; o[6] = (__bf16)v1.z; o[7] = (__bf16)v1.w;
            *(bf16x8*)(Xb + (size_t)i * 8) = o;
        }
    } else {
        // flat_idx sorted -> duplicate runs adjacent; run owner sums fp32, stores bf16.
        int i = (blockIdx.x - cvtBlocks) * blockDim.x + threadIdx.x;
        if (i >= nnz) return;
        const int id = idx[i];
        if (i > 0 && idx[i - 1] == id) return;
        float s = vals[i];
        for (int j = i + 1; j < nnz && idx[j] == id; ++j) s += vals[j];
        W[id] = (__bf16)s;
    }
}

// ---- GEMM: C[M,N] = A[M,K] * B[N,K]^T + bias,  bf16 in / fp32 out ----
// R7 structure (verified 216.5us / 1271 TF / MfmaUtil 58.7 / conflicts 0):
// 256x256 tile, BK=32, 8 waves (2Mx4N), quad-buffered LDS, prefetch distance 3,
// chunk-XOR swizzle, register-double-buffered fragments, source-order interleave
// {VMEM, DS_READ, MFMA} + SGB chains (no setprio inside regions — splits them).
// R10 micro-opt: vmcnt(4) hoisted ABOVE the final 8-MFMA group. Certification
// unchanged (no VMEM issued between wait and barrier -> "<=4 outstanding =>
// STAGE(t+2) landed" still holds at the barrier); residual wait now overlaps
// ~128cyc of MFMA. SGB chain split to match the two scheduling regions the
// asm volatile creates.
// Known dead ends (do not re-attempt): per-wave role if/else (R8: spills loop
// state to scratch, 14x), setprio inside loop (R6: splits SGB region),
// sched_barrier(0) read-pinning (R5: recreates LDS-queue backpressure).
#define BM 256
#define BN 256
#define BK 32
#define NT (IN_F / BK)   // 128 K-tiles

__global__ __launch_bounds__(512, 2) void gemm_bf16_bt(
    const __bf16* __restrict__ A, const __bf16* __restrict__ B,
    const float* __restrict__ bias, float* __restrict__ C,
    int M, int N, int K)
{
    __shared__ __align__(128) __bf16 lds[4][16384];

    const int t512 = threadIdx.x;          // 0..511
    const int wave = t512 >> 6;            // 0..7
    const int lane = t512 & 63;
    const int wm = wave >> 2;              // 0..1  (M half)
    const int wn = wave & 3;               // 0..3  (N quarter)
    const int lq = lane >> 4;              // 0..3
    const int lr = lane & 15;              // 0..15

    // XCD swizzle: grid is exactly 512 = 8 XCDs x 64 contiguous slots
    const int bid  = blockIdx.x;
    const int wgid = (bid & 7) * 64 + (bid >> 3);
    const int mt = wgid >> 4;              // 0..31
    const int nt = wgid & 15;              // 0..15
    const int tileM = mt * BM;
    const int tileN = nt * BN;

    // staging: thread u covers row u>>2; DEST chunk u&3 linear (global_load_lds),
    // SOURCE chunk swizzle-inverse: c = (u&3) ^ ((row>>1)&3) = (u&3) ^ ((u>>3)&3).
    const int srow = t512 >> 2;            // 0..127
    const int scol = ((t512 & 3) ^ ((t512 >> 3) & 3)) * 8;

    const __bf16* gA0 = A + (size_t)(tileM + srow) * K + scol;
    const __bf16* gA1 = A + (size_t)(tileM + 128 + srow) * K + scol;
    const __bf16* gB0 = B + (size_t)(tileN + srow) * K + scol;
    const __bf16* gB1 = B + (size_t)(tileN + 128 + srow) * K + scol;

#define STAGE_A(buf, k0) do { \
        gl_lds_16(gA0 + (k0), &lds[buf][0]    + t512 * 8); \
        gl_lds_16(gA1 + (k0), &lds[buf][4096] + t512 * 8); } while (0)
#define STAGE_B(buf, k0) do { \
        gl_lds_16(gB0 + (k0), &lds[buf][8192]         + t512 * 8); \
        gl_lds_16(gB1 + (k0), &lds[buf][8192 + 4096]  + t512 * 8); } while (0)

    // fragment read offsets with matching XOR (row bases are multiples of 16):
    const int cswz = (lq ^ ((lr >> 1) & 3)) * 8;
    const int aoff = (wm * 128 + lr) * BK + cswz;            // fa[mi] at +mi*512
    const int boff = 8192 + (wn * 64 + lr) * BK + cswz;      // fb[ni] at +ni*512

    f32x4 acc[8][4] = {};
    bf16x8 fa0[8], fb0[4], fa1[8], fb1[4];

#define MM2(FAc, FBc, MI0, MI1) do {                                            \
        _Pragma("unroll") for (int ni_ = 0; ni_ < 4; ++ni_)                     \
            acc[MI0][ni_] = __builtin_amdgcn_mfma_f32_16x16x32_bf16(            \
                FAc[MI0], FBc[ni_], acc[MI0][ni_], 0, 0, 0);                    \
        _Pragma("unroll") for (int ni_ = 0; ni_ < 4; ++ni_)                     \
            acc[MI1][ni_] = __builtin_amdgcn_mfma_f32_16x16x32_bf16(            \
                FAc[MI1], FBc[ni_], acc[MI1][ni_], 0, 0, 0);                    \
    } while (0)

// main-loop tile (tiles 0..123: always stage + always read-ahead), interleaved.
#define TILE_MAIN(T, FAc, FBc, FAn, FBn) do {                                   \
        const int t_ = (T);                                                     \
        const int pb_ = (t_ + 3) & 3; const int pk_ = (t_ + 3) * BK;            \
        const __bf16* nb_ = &lds[(t_ + 1) & 3][0];                              \
        /* ---- region 1: 4 VMEM, 12 DS, 24 MFMA ---- */                        \
        STAGE_A(pb_, pk_);                                                      \
        FAn[0] = *(const bf16x8*)&nb_[aoff];                                    \
        FAn[1] = *(const bf16x8*)&nb_[aoff + 512];                              \
        FBn[0] = *(const bf16x8*)&nb_[boff];                                    \
        MM2(FAc, FBc, 0, 1);                                                    \
        STAGE_B(pb_, pk_);                                                      \
        FBn[1] = *(const bf16x8*)&nb_[boff + 512];                              \
        FBn[2] = *(const bf16x8*)&nb_[boff + 1024];                             \
        FBn[3] = *(const bf16x8*)&nb_[boff + 1536];                             \
        MM2(FAc, FBc, 2, 3);                                                    \
        FAn[2] = *(const bf16x8*)&nb_[aoff + 1024];                             \
        FAn[3] = *(const bf16x8*)&nb_[aoff + 1536];                             \
        FAn[4] = *(const bf16x8*)&nb_[aoff + 2048];                             \
        MM2(FAc, FBc, 4, 5);                                                    \
        FAn[5] = *(const bf16x8*)&nb_[aoff + 2560];                             \
        FAn[6] = *(const bf16x8*)&nb_[aoff + 3072];                             \
        FAn[7] = *(const bf16x8*)&nb_[aoff + 3584];                             \
        __builtin_amdgcn_sched_group_barrier(0x030, 2, 0); /* 2 VMEM  */        \
        __builtin_amdgcn_sched_group_barrier(0x100, 3, 0); /* 3 DS_rd */        \
        __builtin_amdgcn_sched_group_barrier(0x008, 8, 0); /* 8 MFMA  */        \
        __builtin_amdgcn_sched_group_barrier(0x030, 2, 0);                      \
        __builtin_amdgcn_sched_group_barrier(0x100, 3, 0);                      \
        __builtin_amdgcn_sched_group_barrier(0x008, 8, 0);                      \
        __builtin_amdgcn_sched_group_barrier(0x100, 3, 0);                      \
        __builtin_amdgcn_sched_group_barrier(0x008, 8, 0);                      \
        __builtin_amdgcn_sched_group_barrier(0x100, 3, 0);                      \
        /* ---- hoisted wait: overlaps with final MFMA group ---- */            \
        asm volatile("s_waitcnt vmcnt(4)" ::: "memory");                        \
        /* ---- region 2: 8 MFMA (no VMEM -> certification intact) ---- */      \
        MM2(FAc, FBc, 6, 7);                                                    \
        __builtin_amdgcn_sched_group_barrier(0x008, 8, 0);                      \
        __builtin_amdgcn_s_barrier();                                           \
        asm volatile("" ::: "memory");                                          \
    } while (0)

// tail tile: literal T -> all conditionals fold at compile time.
#define TILE(T, FAc, FBc, FAn, FBn) do {                                        \
        const int t_ = (T);                                                     \
        if (t_ + 3 < NT) {                                                      \
            const int pb_ = (t_ + 3) & 3; const int pk_ = (t_ + 3) * BK;        \
            STAGE_A(pb_, pk_); STAGE_B(pb_, pk_);                               \
        }                                                                       \
        if (t_ + 1 < NT) {                                                      \
            const __bf16* nb_ = &lds[(t_ + 1) & 3][0];                          \
            _Pragma("unroll") for (int mi = 0; mi < 8; ++mi)                    \
                FAn[mi] = *(const bf16x8*)&nb_[aoff + mi * 512];                \
            _Pragma("unroll") for (int ni = 0; ni < 4; ++ni)                    \
                FBn[ni] = *(const bf16x8*)&nb_[boff + ni * 512];                \
        }                                                                       \
        _Pragma("unroll") for (int mi = 0; mi < 8; ++mi)                        \
            _Pragma("unroll") for (int ni = 0; ni < 4; ++ni)                    \
                acc[mi][ni] = __builtin_amdgcn_mfma_f32_16x16x32_bf16(          \
                    FAc[mi], FBc[ni], acc[mi][ni], 0, 0, 0);                    \
        if (t_ < NT - 3)       asm volatile("s_waitcnt vmcnt(4)" ::: "memory"); \
        else if (t_ == NT - 3) asm volatile("s_waitcnt vmcnt(0)" ::: "memory"); \
        if (t_ < NT - 1) {                                                      \
            __builtin_amdgcn_s_barrier();                                       \
            asm volatile("" ::: "memory");                                      \
        }                                                                       \
    } while (0)

    // ---- prologue: stage 0,1,2; certify stages 0+1 for ALL waves; frags(0) ----
    STAGE_A(0, 0);   STAGE_B(0, 0);
    STAGE_A(1, 32);  STAGE_B(1, 32);
    STAGE_A(2, 64);  STAGE_B(2, 64);
    asm volatile("s_waitcnt vmcnt(4)" ::: "memory");
    __builtin_amdgcn_s_barrier();
    asm volatile("" ::: "memory");
    {
        const __bf16* nb_ = &lds[0][0];
#pragma unroll
        for (int mi = 0; mi < 8; ++mi) fa0[mi] = *(const bf16x8*)&nb_[aoff + mi * 512];
#pragma unroll
        for (int ni = 0; ni < 4; ++ni) fb0[ni] = *(const bf16x8*)&nb_[boff + ni * 512];
    }

    // main loop: tiles 0..123 (t+3 <= 126 < NT and t+1 <= 124 < NT always)
    for (int t = 0; t < 124; t += 2) {
        TILE_MAIN(t,     fa0, fb0, fa1, fb1);
        TILE_MAIN(t + 1, fa1, fb1, fa0, fb0);
    }
    // tail: tiles 124..127, literal-folded conditionals
    TILE(124, fa0, fb0, fa1, fb1);
    TILE(125, fa1, fb1, fa0, fb0);
    TILE(126, fa0, fb0, fa1, fb1);
    TILE(127, fa1, fb1, fa0, fb0);

    // ---- epilogue: C/D layout col=lane&15, row=(lane>>4)*4+reg  [m89-verified] ----
    float bv[4];
#pragma unroll
    for (int ni = 0; ni < 4; ++ni) bv[ni] = bias[tileN + wn * 64 + ni * 16 + lr];
#pragma unroll
    for (int mi = 0; mi < 8; ++mi) {
#pragma unroll
        for (int ni = 0; ni < 4; ++ni) {
            const int gn = tileN + wn * 64 + ni * 16 + lr;
#pragma unroll
            for (int r = 0; r < 4; ++r) {
                const int gm = tileM + wm * 128 + mi * 16 + lq * 4 + r;
                C[(size_t)gm * N + gn] = acc[mi][ni][r] + bv[ni];
            }
        }
    }
#undef TILE
#undef TILE_MAIN
#undef MM2
#undef STAGE_A
#undef STAGE_B
}

extern "C" void kernel_launch(void* const* d_in, const int* in_sizes, int n_in,
                              void* d_out, int out_size, void* d_ws, size_t ws_size,
                              hipStream_t stream) {
    const float* x    = (const float*)d_in[0];   // (4,2048,4096) fp32
    const float* vals = (const float*)d_in[1];   // (NNZ,) fp32
    const float* bias = (const float*)d_in[2];   // (4096,) fp32
    const int*   idx  = (const int*)d_in[3];     // (NNZ,) sorted flat indices
    float* out = (float*)d_out;                  // (4,2048,4096) fp32

    const int nnz = in_sizes[1];
    const int K = IN_F, N = OUT_F;
    const int M = in_sizes[0] / K;               // 8192

    // workspace: [0,32M) W bf16 | [32M,96M) x bf16
    char* ws = (char*)d_ws;
    __bf16* Wb = (__bf16*)ws;
    __bf16* Xb = (__bf16*)(ws + (size_t)32 * 1024 * 1024);

    const int wElems = N * K;                    // 16777216
    const int xElems = M * K;                    // 33554432
    const int n8 = xElems / 8;                   // 4194304 cvt threads
    const int cvtBlocks = n8 / 256;              // 16384
    const int scatBlocks = (nnz + 255) / 256;    // 6554

    hipMemsetAsync(Wb, 0, (size_t)wElems * sizeof(__bf16), stream);
    cvt_and_scatter<<<cvtBlocks + scatBlocks, 256, 0, stream>>>(
        x, Xb, n8, vals, idx, Wb, nnz, cvtBlocks);

    gemm_bf16_bt<<<(M / BM) * (N / BN), 512, 0, stream>>>(Xb, Wb, bias, out, M, N, K);
}